// Round 9
// baseline (516.231 us; speedup 1.0000x reference)
//
#include <hip/hip_runtime.h>

// TranslationInvariantMP, 4-pass linearity split (MI355X/gfx950):
//   A: y0 = x @ W0            (LDS-free matvec, W in VGPRs, row via L1 broadcast)
//   B: h0 = elu(agg_TI(y0))   (gather-agg, deep pipeline @ 128-VGPR budget)
//   C: z  = h0 @ W1
//   D: h1 = elu(agg(z) + b1)
// agg is linear => agg(x)@W == agg(x@W).

constexpr int VN  = 100000;
constexpr int KN  = 32;
constexpr int FN  = 64;
constexpr int WPB = 4;               // waves per block
constexpr int TPW = 8;               // vertices per wave (gather)
constexpr int VPB = WPB * TPW;       // 32 vertices per block -> 3125 blocks exact

__device__ float g_scratch[(size_t)VN * FN];   // 25.6 MB fallback if ws too small

template <bool FIRST, bool BIAS>
__global__ __launch_bounds__(256, 4)   // 128-VGPR budget -> deep gather pipeline
void gather_agg(const float* __restrict__ src,    // [VN][64] compact, 256B rows
                const int*   __restrict__ nbidx,  // [VN][32] int32
                const float* __restrict__ distsq, // [VN][32] f32
                const float* __restrict__ bias,   // [64] (BIAS only)
                float*       __restrict__ out,    // [VN][128]
                int out_col)
{
    const int lane = threadIdx.x & 63;
    const int wid  = threadIdx.x >> 6;
    const int tq   = lane >> 4;        // vertex within quad (0..3)
    const int fq   = lane & 15;        // float4 index within feature row

    // 8 vertices x 34 (w, byte-offset) pairs (stride 68 floats = 272B)
    __shared__ float s_wo[WPB][TPW * 68];

    const int vbase = (blockIdx.x * WPB + wid) * TPW;

    // ---- stage all 256 (w, offset) pairs for this wave's 8 vertices ----
    {
        float4 d4 = ((const float4*)(distsq + (size_t)vbase * KN))[lane];
        int4   i4 = ((const int4*)  (nbidx  + (size_t)vbase * KN))[lane];
        const int s = 4 * lane;                       // first flat k-slot
        float* dst = s_wo[wid] + (s >> 5) * 68 + (s & 31) * 2;
        float4 lo, hi;
        lo.x = __expf(-10.0f * d4.x); lo.y = __int_as_float(i4.x * (FN * 4));
        lo.z = __expf(-10.0f * d4.y); lo.w = __int_as_float(i4.y * (FN * 4));
        hi.x = __expf(-10.0f * d4.z); hi.y = __int_as_float(i4.z * (FN * 4));
        hi.z = __expf(-10.0f * d4.w); hi.w = __int_as_float(i4.w * (FN * 4));
        ((float4*)dst)[0] = lo;
        ((float4*)dst)[1] = hi;
        // same-wave DS in-order: reads below see these writes (no barrier needed)
    }

    const float invK = 1.0f / KN;
    float4 b4 = {0, 0, 0, 0};
    if (BIAS) b4 = ((const float4*)bias)[fq];
    const char* sb = (const char*)src + (size_t)fq * 16;

#pragma unroll
    for (int g = 0; g < 2; ++g) {
        const int vl = g * 4 + tq;                    // vertex slot in wave
        const int vt = vbase + vl;
        const float* wo = s_wo[wid] + vl * 68;

        float4 a0 = {0, 0, 0, 0}, a1 = {0, 0, 0, 0};
        float  ws0 = 0.0f, ws1 = 0.0f;
#pragma unroll
        for (int k = 0; k < KN; k += 2) {
            float4 p = *(const float4*)(wo + 2 * k);  // {w_k, o_k, w_k1, o_k1}
            float4 x0 = *(const float4*)(sb + __float_as_int(p.y));
            float4 x1 = *(const float4*)(sb + __float_as_int(p.w));
            a0.x += p.x * x0.x; a0.y += p.x * x0.y;
            a0.z += p.x * x0.z; a0.w += p.x * x0.w;
            a1.x += p.z * x1.x; a1.y += p.z * x1.y;
            a1.z += p.z * x1.z; a1.w += p.z * x1.w;
            if (FIRST) { ws0 += p.x; ws1 += p.z; }
        }
        float4 acc;
        acc.x = a0.x + a1.x; acc.y = a0.y + a1.y;
        acc.z = a0.z + a1.z; acc.w = a0.w + a1.w;

        if (FIRST) {
            // translation invariance: acc -= y0_v * sum_k w_k
            const float wsum = ws0 + ws1;
            float4 self = *(const float4*)((const char*)src + (size_t)vt * (FN * 4) + fq * 16);
            acc.x -= self.x * wsum; acc.y -= self.y * wsum;
            acc.z -= self.z * wsum; acc.w -= self.w * wsum;
        }

        float4 h;
        h.x = acc.x * invK; h.y = acc.y * invK;
        h.z = acc.z * invK; h.w = acc.w * invK;
        if (BIAS) { h.x += b4.x; h.y += b4.y; h.z += b4.z; h.w += b4.w; }
        h.x = (h.x > 0.0f) ? h.x : __expf(h.x) - 1.0f;
        h.y = (h.y > 0.0f) ? h.y : __expf(h.y) - 1.0f;
        h.z = (h.z > 0.0f) ? h.z : __expf(h.z) - 1.0f;
        h.w = (h.w > 0.0f) ? h.w : __expf(h.w) - 1.0f;

        *(float4*)(out + (size_t)vt * 128 + out_col + fq * 4) = h;
    }
}

// dst[v][j] = sum_f src[v][f] * W[f][j]  — LDS-free: W column in VGPRs,
// x-row read by all 64 lanes at the SAME address (TA merges; L1-resident).
constexpr int MM_BLOCKS = 1600;                 // 6400 waves
constexpr int MM_VPW    = 16;                   // vertices per wave (6400*16 >= VN)

__global__ __launch_bounds__(256, 4)
void matmul64s(const float* __restrict__ src, int sstride,   // floats per row
               const float* __restrict__ W,                  // [64][64]
               float*       __restrict__ dst, int dstride)
{
    const int lane  = threadIdx.x & 63;
    const int gwave = blockIdx.x * WPB + (threadIdx.x >> 6);

    float wreg[FN];                         // lane j holds W[:,j]
#pragma unroll
    for (int f = 0; f < FN; ++f) wreg[f] = W[f * FN + lane];

    const int v0 = gwave * MM_VPW;
#pragma unroll 2
    for (int i = 0; i < MM_VPW; ++i) {
        const int v = v0 + i;
        if (v >= VN) break;                 // wave-uniform
        const float4* row = (const float4*)(src + (size_t)v * sstride);
        float h0 = 0.f, h1 = 0.f, h2 = 0.f, h3 = 0.f;
#pragma unroll
        for (int f4 = 0; f4 < 16; f4 += 4) {
            float4 a0 = row[f4 + 0], a1 = row[f4 + 1];
            float4 a2 = row[f4 + 2], a3 = row[f4 + 3];
            h0 += a0.x * wreg[4*f4 + 0]  + a0.y * wreg[4*f4 + 1]
                + a0.z * wreg[4*f4 + 2]  + a0.w * wreg[4*f4 + 3];
            h1 += a1.x * wreg[4*f4 + 4]  + a1.y * wreg[4*f4 + 5]
                + a1.z * wreg[4*f4 + 6]  + a1.w * wreg[4*f4 + 7];
            h2 += a2.x * wreg[4*f4 + 8]  + a2.y * wreg[4*f4 + 9]
                + a2.z * wreg[4*f4 + 10] + a2.w * wreg[4*f4 + 11];
            h3 += a3.x * wreg[4*f4 + 12] + a3.y * wreg[4*f4 + 13]
                + a3.z * wreg[4*f4 + 14] + a3.w * wreg[4*f4 + 15];
        }
        dst[(size_t)v * dstride + lane] = (h0 + h1) + (h2 + h3);
    }
}

extern "C" void kernel_launch(void* const* d_in, const int* in_sizes, int n_in,
                              void* d_out, int out_size, void* d_ws, size_t ws_size,
                              hipStream_t stream) {
    const float* x   = (const float*)d_in[0];
    const int*   nb  = (const int*)  d_in[1];
    const float* dsq = (const float*)d_in[2];
    const float* W0  = (const float*)d_in[3];
    const float* W1  = (const float*)d_in[4];
    const float* b1  = (const float*)d_in[5];
    float* out = (float*)d_out;

    const size_t need = (size_t)VN * FN * sizeof(float);
    float* ws = (ws_size >= need) ? (float*)d_ws : g_scratch;

    const int gblocks = VN / VPB;   // 3125 exact

    // A: y0 = x @ W0 -> ws
    matmul64s<<<MM_BLOCKS, 256, 0, stream>>>(x, FN, W0, ws, FN);
    // B: h0 = elu(TI-agg(y0)) -> out[:, 0:64]
    gather_agg<true, false><<<gblocks, 256, 0, stream>>>(ws, nb, dsq, nullptr, out, 0);
    // C: z = h0 @ W1 -> ws   (h0 rows at out[v][0:64], stride 128)
    matmul64s<<<MM_BLOCKS, 256, 0, stream>>>(out, 2 * FN, W1, ws, FN);
    // D: h1 = elu(agg(z) + b1) -> out[:, 64:128]
    gather_agg<false, true><<<gblocks, 256, 0, stream>>>(ws, nb, dsq, b1, out, 64);
}